// Round 12
// baseline (344.838 us; speedup 1.0000x reference)
//
#include <hip/hip_runtime.h>
#include <math.h>

#define NEG 0.2f

typedef short bf16x8 __attribute__((ext_vector_type(8)));
typedef float f32x4  __attribute__((ext_vector_type(4)));

// ---------------------------------------------------------------------------
// helpers
// ---------------------------------------------------------------------------
static __device__ __forceinline__ void fma4(float4& d, float s, const float4 w) {
    d.x = fmaf(s, w.x, d.x); d.y = fmaf(s, w.y, d.y);
    d.z = fmaf(s, w.z, d.z); d.w = fmaf(s, w.w, d.w);
}
// leaky relu of (a+b): max(v, 0.2v) — valid since slope in (0,1)
static __device__ __forceinline__ float4 lrelu4(float4 a, float4 b) {
    float4 r; float v;
    v = a.x + b.x; r.x = fmaxf(v, NEG * v);
    v = a.y + b.y; r.y = fmaxf(v, NEG * v);
    v = a.z + b.z; r.z = fmaxf(v, NEG * v);
    v = a.w + b.w; r.w = fmaxf(v, NEG * v);
    return r;
}
static __device__ __forceinline__ unsigned short f2bf(float f) {   // RNE, finite
    unsigned int x = __float_as_uint(f);
    unsigned int r = (x + 0x7FFFu + ((x >> 16) & 1u)) >> 16;
    return (unsigned short)r;
}
static __device__ __forceinline__ float rlane(float v, int l) {
    return __int_as_float(__builtin_amdgcn_readlane(__float_as_int(v), l));
}

// Sum across each 16-lane DPP row (head h = lanes 16h..16h+15).
#define DPP_ADD(x, ctrl) \
    ((x) + __int_as_float(__builtin_amdgcn_update_dpp( \
        __float_as_int(x), __float_as_int(x), (ctrl), 0xF, 0xF, true)))
static __device__ __forceinline__ float rowsum16(float v) {
    v = DPP_ADD(v, 0xB1);   // quad_perm xor1
    v = DPP_ADD(v, 0x4E);   // quad_perm xor2
    v = DPP_ADD(v, 0x141);  // row_half_mirror
    v = DPP_ADD(v, 0x140);  // row_mirror
    return v;
}

// ---------------------------------------------------------------------------
// CSR build (separate dispatches; cooperative grid.sync was ~120us/sync, R7)
// ---------------------------------------------------------------------------
__global__ void k_hist_wt(const int* __restrict__ dst_s, int Es,
                          const int* __restrict__ dst_n, int En,
                          int* __restrict__ deg_s, int* __restrict__ deg_n,
                          const float* __restrict__ W, unsigned short* __restrict__ Wt) {
    int i = blockIdx.x * 256 + threadIdx.x;
    if (i < Es) atomicAdd(&deg_s[dst_s[i]], 1);
    int j = i - Es;
    if (j >= 0 && j < En) atomicAdd(&deg_n[dst_n[j]], 1);
    if (i < 512 * 256) {                 // W[512][256] f32 -> Wt[256][512] bf16
        int k = i >> 8, n = i & 255;
        Wt[(size_t)n * 512 + k] = f2bf(W[i]);
    }
}

__global__ __launch_bounds__(1024) void k_scan2(int* a, int na, int* b, int nb) {
    int* p = (blockIdx.x == 0) ? a : b;
    int n  = (blockIdx.x == 0) ? na : nb;
    __shared__ int sums[1024];
    int t = threadIdx.x;
    int C = (n + 1023) >> 10;
    int base = t * C;
    int s = 0;
    for (int j = 0; j < C; ++j) { int i = base + j; if (i < n) s += p[i]; }
    sums[t] = s;
    __syncthreads();
    for (int off = 1; off < 1024; off <<= 1) {
        int v = (t >= off) ? sums[t - off] : 0;
        __syncthreads();
        sums[t] += v;
        __syncthreads();
    }
    int run = (t == 0) ? 0 : sums[t - 1];
    for (int j = 0; j < C; ++j) {
        int i = base + j;
        if (i < n) { int v = p[i]; p[i] = run; run += v; }
    }
}

__global__ void k_scatter(const int* __restrict__ src_s, const int* __restrict__ dst_s, int Es,
                          const int* __restrict__ src_n, const int* __restrict__ dst_n, int En,
                          int* __restrict__ cur_s, int* __restrict__ cur_n,
                          int* __restrict__ csr_s, int* __restrict__ csr_n) {
    int i = blockIdx.x * 256 + threadIdx.x;
    if (i < Es) {
        int pos = atomicAdd(&cur_s[dst_s[i]], 1);
        csr_s[pos] = src_s[i];
    }
    int j = i - Es;
    if (j >= 0 && j < En) {
        int pos = atomicAdd(&cur_n[dst_n[j]], 1);
        csr_n[pos] = src_n[j];
    }
}

// ---------------------------------------------------------------------------
// GATv2, both layers fused by contiguous block ranges (block < gNs -> seen).
// R12: ONE-WAVE blocks (64 thr), 8 nodes/wave in two 4-node groups.
// Rationale: R9/R11 both pinned at occupancy 18% / VALUBusy 63% -- 4-wave
// blocks retire at max(wave times); degree variance leaves idle-resident
// waves holding SIMD slots. 1-wave blocks recycle slots individually and
// amortize the prologue over 8 nodes. Edge loop = R9's verified no-spill
// lanes-as-row-buffer (1-VGPR double buffer); fd/fr via one-pass weight
// stream with 4-node lane gather (R9); no online max (|score| bounded).
// ---------------------------------------------------------------------------
__global__ __launch_bounds__(64) void k_gat(
    const float* __restrict__ xsrc_s, const int* __restrict__ pfx_s, const int* __restrict__ csr_s,
    const float* __restrict__ Ws_s, const float* __restrict__ bs_s,
    const float* __restrict__ Wd_s, const float* __restrict__ bd_s,
    const float* __restrict__ at_s,
    const float* __restrict__ Wr_s, const float* __restrict__ br_s,
    const float* __restrict__ xsrc_n, const int* __restrict__ pfx_n, const int* __restrict__ csr_n,
    const float* __restrict__ Ws_n, const float* __restrict__ bs_n,
    const float* __restrict__ Wd_n, const float* __restrict__ bd_n,
    const float* __restrict__ at_n,
    const float* __restrict__ Wr_n, const float* __restrict__ br_n,
    const float* __restrict__ x_ag,
    unsigned short* __restrict__ xcat, int n_dst, int gNs)
{
    const bool seen = (int)blockIdx.x < gNs;
    const float* x_src = seen ? xsrc_s : xsrc_n;
    const int*   pfx   = seen ? pfx_s  : pfx_n;
    const int*   csr   = seen ? csr_s  : csr_n;
    const float* Ws    = seen ? Ws_s   : Ws_n;
    const float* bs    = seen ? bs_s   : bs_n;
    const float* Wd    = seen ? Wd_s   : Wd_n;
    const float* bd    = seen ? bd_s   : bd_n;
    const float* at    = seen ? at_s   : at_n;
    const float* Wr    = seen ? Wr_s   : Wr_n;
    const float* br    = seen ? br_s   : br_n;
    const int col = seen ? 0 : 256;
    const int blk = seen ? (int)blockIdx.x : (int)blockIdx.x - gNs;

    const int lane = threadIdx.x;    // 0..63, one wave per block
    const int d0 = lane * 4;

    // wave-lifetime constants (amortized over 8 nodes)
    float4 ws_r[8];
#pragma unroll
    for (int k = 0; k < 8; ++k) ws_r[k] = *(const float4*)&Ws[k * 256 + d0];
    const float4 bsv = *(const float4*)&bs[d0];
    const float4 atv = *(const float4*)&at[d0];
    const float4 bdv = *(const float4*)&bd[d0];
    const float4 brv = *(const float4*)&br[d0];

    for (int g = 0; g < 2; ++g) {
        const int nodeBase = blk * 8 + g * 4;
        if (nodeBase >= n_dst) break;

        // ---- gather the group's 4 agent rows: lane L = feat L&15 of node L>>4
        int gn = nodeBase + (lane >> 4);
        gn = (gn < n_dst) ? gn : n_dst - 1;
        float xag = x_ag[(size_t)gn * 16 + (lane & 15)];

        // ---- prefetch the 4 nodes' edge ranges (overlaps fd/fr pass)
        int e_start[4], e_end[4];
#pragma unroll
        for (int j = 0; j < 4; ++j) {
            int nd = nodeBase + j;
            nd = (nd < n_dst) ? nd : n_dst - 1;
            e_end[j]   = pfx[nd];
            e_start[j] = nd ? pfx[nd - 1] : 0;
        }

        // ---- fd/fr for the 4 nodes in ONE pass over the 32 weight rows
        float4 fd4[4], fr4[4];
#pragma unroll
        for (int j = 0; j < 4; ++j) { fd4[j] = bdv; fr4[j] = brv; }
#pragma unroll
        for (int k = 0; k < 16; ++k) {
            float4 wd = *(const float4*)&Wd[k * 256 + d0];
            float4 wr = *(const float4*)&Wr[k * 256 + d0];
#pragma unroll
            for (int j = 0; j < 4; ++j) {
                float xk = rlane(xag, j * 16 + k);
                fma4(fd4[j], xk, wd);
                fma4(fr4[j], xk, wr);
            }
        }

#pragma unroll
        for (int rep = 0; rep < 4; ++rep) {
            const int node = nodeBase + rep;
            if (node >= n_dst) break;

            const int start = e_start[rep];
            const int deg   = e_end[rep] - start;
            const float4 fd = fd4[rep];
            const float4 fr = fr4[rep];

            float l = 0.f;
            float4 acc = make_float4(0.f, 0.f, 0.f, 0.f);

            if (deg > 0) {
                const int gs = lane >> 3;   // edge slot 0..7 within chunk
                const int w8 = lane & 7;    // word within the 8-float row

                int e0 = (gs < deg) ? gs : deg - 1;
                int i0 = csr[start + e0];
                float r0 = x_src[(size_t)i0 * 8 + w8];    // 8 rows in flight
                int e1 = (8 + gs < deg) ? 8 + gs : deg - 1;
                int i1 = csr[start + e1];

                for (int base = 0; base < deg; base += 8) {
                    float r1 = x_src[(size_t)i1 * 8 + w8];
                    int e2 = base + 16 + gs; e2 = (e2 < deg) ? e2 : deg - 1;
                    int i2 = csr[start + e2];

#pragma unroll
                    for (int j = 0; j < 8; ++j) {
                        if (base + j < deg) {   // wave-uniform -> scalar branch
                            float x0 = rlane(r0, j * 8 + 0);
                            float x1 = rlane(r0, j * 8 + 1);
                            float x2 = rlane(r0, j * 8 + 2);
                            float x3 = rlane(r0, j * 8 + 3);
                            float x4 = rlane(r0, j * 8 + 4);
                            float x5 = rlane(r0, j * 8 + 5);
                            float x6 = rlane(r0, j * 8 + 6);
                            float x7 = rlane(r0, j * 8 + 7);

                            float4 fs = bsv;
                            fma4(fs, x0, ws_r[0]);
                            fma4(fs, x1, ws_r[1]);
                            fma4(fs, x2, ws_r[2]);
                            fma4(fs, x3, ws_r[3]);
                            fma4(fs, x4, ws_r[4]);
                            fma4(fs, x5, ws_r[5]);
                            fma4(fs, x6, ws_r[6]);
                            fma4(fs, x7, ws_r[7]);

                            float4 tt = lrelu4(fs, fd);
                            float sc = tt.x * atv.x;
                            sc = fmaf(tt.y, atv.y, sc);
                            sc = fmaf(tt.z, atv.z, sc);
                            sc = fmaf(tt.w, atv.w, sc);
                            sc = rowsum16(sc);

                            float p = __expf(sc);   // no max shift: |sc| bounded
                            l += p;
                            acc.x = fmaf(p, fs.x, acc.x);
                            acc.y = fmaf(p, fs.y, acc.y);
                            acc.z = fmaf(p, fs.z, acc.z);
                            acc.w = fmaf(p, fs.w, acc.w);
                        }
                    }
                    r0 = r1; i1 = i2;
                }
            }

            float inv = (l > 0.f) ? 1.f / l : 0.f;   // zero in-degree -> rst = 0
            ushort4 o;
            o.x = f2bf(fmaxf(fmaf(acc.x, inv, fr.x), 0.f));
            o.y = f2bf(fmaxf(fmaf(acc.y, inv, fr.y), 0.f));
            o.z = f2bf(fmaxf(fmaf(acc.z, inv, fr.z), 0.f));
            o.w = f2bf(fmaxf(fmaf(acc.w, inv, fr.w), 0.f));
            *(ushort4*)&xcat[(size_t)node * 512 + col + d0] = o;
        }
    }
}

// ---------------------------------------------------------------------------
// out = relu(X[M,512]bf16 @ W[512,256]bf16 + b) via mfma_f32_16x16x32_bf16.
// Block = 4 waves: rows rbase..rbase+15, wave w covers cols 64w..64w+63.
// A/B frags straight from L2 (no LDS). D: col n=lane&15, row m=q*4+reg.
// ---------------------------------------------------------------------------
__global__ __launch_bounds__(256) void k_mlp(
    const unsigned short* __restrict__ X, const unsigned short* __restrict__ Wt,
    const float* __restrict__ b, float* __restrict__ out, int M)
{
    const int t = threadIdx.x;
    const int wave = t >> 6, lane = t & 63;
    const int m16 = lane & 15, q = lane >> 4;
    const int rbase = blockIdx.x * 16;
    const int nbase = wave * 64;

    int rowa = rbase + m16; if (rowa >= M) rowa = M - 1;
    const unsigned short* xp = X + (size_t)rowa * 512 + q * 8;
    const unsigned short* w0 = Wt + (size_t)(nbase + m16) * 512 + q * 8;
    const unsigned short* w1 = w0 + 16 * 512;
    const unsigned short* w2 = w0 + 32 * 512;
    const unsigned short* w3 = w0 + 48 * 512;

    f32x4 ac0 = {0.f, 0.f, 0.f, 0.f}, ac1 = ac0, ac2 = ac0, ac3 = ac0;

#pragma unroll
    for (int k0 = 0; k0 < 512; k0 += 32) {
        bf16x8 a  = *(const bf16x8*)(xp + k0);
        bf16x8 b0 = *(const bf16x8*)(w0 + k0);
        bf16x8 b1 = *(const bf16x8*)(w1 + k0);
        bf16x8 b2 = *(const bf16x8*)(w2 + k0);
        bf16x8 b3 = *(const bf16x8*)(w3 + k0);
        ac0 = __builtin_amdgcn_mfma_f32_16x16x32_bf16(a, b0, ac0, 0, 0, 0);
        ac1 = __builtin_amdgcn_mfma_f32_16x16x32_bf16(a, b1, ac1, 0, 0, 0);
        ac2 = __builtin_amdgcn_mfma_f32_16x16x32_bf16(a, b2, ac2, 0, 0, 0);
        ac3 = __builtin_amdgcn_mfma_f32_16x16x32_bf16(a, b3, ac3, 0, 0, 0);
    }

#define EPI(AC, J) { \
        int coln = nbase + (J) * 16 + m16; \
        float bias = b[coln]; \
        _Pragma("unroll") \
        for (int r = 0; r < 4; ++r) { \
            int orow = rbase + q * 4 + r; \
            if (orow < M) \
                out[(size_t)orow * 256 + coln] = fmaxf(AC[r] + bias, 0.f); \
        } }
    EPI(ac0, 0) EPI(ac1, 1) EPI(ac2, 2) EPI(ac3, 3)
#undef EPI
}

// ---------------------------------------------------------------------------
extern "C" void kernel_launch(void* const* d_in, const int* in_sizes, int n_in,
                              void* d_out, int out_size, void* d_ws, size_t ws_size,
                              hipStream_t stream) {
    const float* x_gt   = (const float*)d_in[0];
    const float* x_ubs  = (const float*)d_in[1];
    const float* x_ag   = (const float*)d_in[2];
    const int* seen_src = (const int*)d_in[3];
    const int* seen_dst = (const int*)d_in[4];
    const int* near_src = (const int*)d_in[5];
    const int* near_dst = (const int*)d_in[6];
    const float* Ws_s = (const float*)d_in[7];  const float* bs_s = (const float*)d_in[8];
    const float* Wd_s = (const float*)d_in[9];  const float* bd_s = (const float*)d_in[10];
    const float* at_s = (const float*)d_in[11];
    const float* Wr_s = (const float*)d_in[12]; const float* br_s = (const float*)d_in[13];
    const float* Ws_n = (const float*)d_in[14]; const float* bs_n = (const float*)d_in[15];
    const float* Wd_n = (const float*)d_in[16]; const float* bd_n = (const float*)d_in[17];
    const float* at_n = (const float*)d_in[18];
    const float* Wr_n = (const float*)d_in[19]; const float* br_n = (const float*)d_in[20];
    const float* W_a  = (const float*)d_in[21]; const float* b_a  = (const float*)d_in[22];

    const int n_ag = in_sizes[2] / 16;
    const int E_s  = in_sizes[3];
    const int E_n  = in_sizes[5];

    char* ws = (char*)d_ws;
    int* cur_s = (int*)ws;              ws += (size_t)n_ag * 4;
    int* cur_n = (int*)ws;              ws += (size_t)n_ag * 4;
    int* csr_s = (int*)ws;              ws += (size_t)E_s * 4;
    int* csr_n = (int*)ws;              ws += (size_t)E_n * 4;
    unsigned short* xcat = (unsigned short*)ws;  ws += (size_t)n_ag * 512 * 2;
    unsigned short* Wt   = (unsigned short*)ws;  // [256][512] bf16

    hipMemsetAsync(cur_s, 0, (size_t)n_ag * 8, stream);  // cur_s, cur_n contiguous

    int gE = (E_s + E_n + 255) / 256;
    k_hist_wt<<<gE, 256, 0, stream>>>(seen_dst, E_s, near_dst, E_n, cur_s, cur_n, W_a, Wt);
    k_scan2<<<2, 1024, 0, stream>>>(cur_s, n_ag, cur_n, n_ag);
    k_scatter<<<gE, 256, 0, stream>>>(seen_src, seen_dst, E_s, near_src, near_dst, E_n,
                                      cur_s, cur_n, csr_s, csr_n);

    int gN = (n_ag + 7) / 8;   // 8 nodes per 1-wave block
    k_gat<<<2 * gN, 64, 0, stream>>>(
        x_gt,  cur_s, csr_s, Ws_s, bs_s, Wd_s, bd_s, at_s, Wr_s, br_s,
        x_ubs, cur_n, csr_n, Ws_n, bs_n, Wd_n, bd_n, at_n, Wr_n, br_n,
        x_ag, xcat, n_ag, gN);

    k_mlp<<<(n_ag + 15) / 16, 256, 0, stream>>>(xcat, Wt, b_a, (float*)d_out, n_ag);
}

// Round 13
// 310.200 us; speedup vs baseline: 1.1117x; 1.1117x over previous
//
#include <hip/hip_runtime.h>
#include <math.h>

#define NEG 0.2f

typedef short bf16x8 __attribute__((ext_vector_type(8)));
typedef float f32x4  __attribute__((ext_vector_type(4)));
typedef float f32x2  __attribute__((ext_vector_type(2)));

// ---------------------------------------------------------------------------
// helpers
// ---------------------------------------------------------------------------
static __device__ __forceinline__ void fma4(float4& d, float s, const float4 w) {
    d.x = fmaf(s, w.x, d.x); d.y = fmaf(s, w.y, d.y);
    d.z = fmaf(s, w.z, d.z); d.w = fmaf(s, w.w, d.w);
}
static __device__ __forceinline__ f32x2 pkfma(f32x2 a, f32x2 b, f32x2 c) {
    return __builtin_elementwise_fma(a, b, c);   // -> v_pk_fma_f32
}
static __device__ __forceinline__ f32x2 splat2(float x) { return (f32x2){x, x}; }

static __device__ __forceinline__ unsigned short f2bf(float f) {   // RNE, finite
    unsigned int x = __float_as_uint(f);
    unsigned int r = (x + 0x7FFFu + ((x >> 16) & 1u)) >> 16;
    return (unsigned short)r;
}
static __device__ __forceinline__ float rlane(float v, int l) {
    return __int_as_float(__builtin_amdgcn_readlane(__float_as_int(v), l));
}

// Sum across each 16-lane DPP row (head h = lanes 16h..16h+15).
#define DPP_ADD(x, ctrl) \
    ((x) + __int_as_float(__builtin_amdgcn_update_dpp( \
        __float_as_int(x), __float_as_int(x), (ctrl), 0xF, 0xF, true)))
static __device__ __forceinline__ float rowsum16(float v) {
    v = DPP_ADD(v, 0xB1);   // quad_perm xor1
    v = DPP_ADD(v, 0x4E);   // quad_perm xor2
    v = DPP_ADD(v, 0x141);  // row_half_mirror
    v = DPP_ADD(v, 0x140);  // row_mirror
    return v;
}

// ---------------------------------------------------------------------------
// CSR build (separate dispatches; cooperative grid.sync was ~120us/sync, R7)
// ---------------------------------------------------------------------------
__global__ void k_hist_wt(const int* __restrict__ dst_s, int Es,
                          const int* __restrict__ dst_n, int En,
                          int* __restrict__ deg_s, int* __restrict__ deg_n,
                          const float* __restrict__ W, unsigned short* __restrict__ Wt) {
    int i = blockIdx.x * 256 + threadIdx.x;
    if (i < Es) atomicAdd(&deg_s[dst_s[i]], 1);
    int j = i - Es;
    if (j >= 0 && j < En) atomicAdd(&deg_n[dst_n[j]], 1);
    if (i < 512 * 256) {                 // W[512][256] f32 -> Wt[256][512] bf16
        int k = i >> 8, n = i & 255;
        Wt[(size_t)n * 512 + k] = f2bf(W[i]);
    }
}

__global__ __launch_bounds__(1024) void k_scan2(int* a, int na, int* b, int nb) {
    int* p = (blockIdx.x == 0) ? a : b;
    int n  = (blockIdx.x == 0) ? na : nb;
    __shared__ int sums[1024];
    int t = threadIdx.x;
    int C = (n + 1023) >> 10;
    int base = t * C;
    int s = 0;
    for (int j = 0; j < C; ++j) { int i = base + j; if (i < n) s += p[i]; }
    sums[t] = s;
    __syncthreads();
    for (int off = 1; off < 1024; off <<= 1) {
        int v = (t >= off) ? sums[t - off] : 0;
        __syncthreads();
        sums[t] += v;
        __syncthreads();
    }
    int run = (t == 0) ? 0 : sums[t - 1];
    for (int j = 0; j < C; ++j) {
        int i = base + j;
        if (i < n) { int v = p[i]; p[i] = run; run += v; }
    }
}

__global__ void k_scatter(const int* __restrict__ src_s, const int* __restrict__ dst_s, int Es,
                          const int* __restrict__ src_n, const int* __restrict__ dst_n, int En,
                          int* __restrict__ cur_s, int* __restrict__ cur_n,
                          int* __restrict__ csr_s, int* __restrict__ csr_n) {
    int i = blockIdx.x * 256 + threadIdx.x;
    if (i < Es) {
        int pos = atomicAdd(&cur_s[dst_s[i]], 1);
        csr_s[pos] = src_s[i];
    }
    int j = i - Es;
    if (j >= 0 && j < En) {
        int pos = atomicAdd(&cur_n[dst_n[j]], 1);
        csr_n[pos] = src_n[j];
    }
}

// ---------------------------------------------------------------------------
// GATv2, both layers fused by contiguous block ranges (block < gNs -> seen).
// R13 = R9's exact structure (4-wave blocks, 4 nodes/wave -- the best
// measured config: 89us, VALUBusy 63%; R12's 1-wave blocks regressed to
// occupancy 10%) with the edge math and fd/fr prologue rewritten in f32x2
// packed ops (v_pk_fma_f32 etc., full-rate on gfx950) -- halves the
// FMA-class VALU issue count (~77 -> ~52 instr/edge). Splat operands are
// wave-uniform SGPRs (readlane) -> op_sel_hi broadcast, near-free.
// Edge loop: lanes-as-row-buffer, 1-VGPR double buffer (no-spill, R6).
// No online max (|score| bounded -> exp safe, verified R6-R12).
// ---------------------------------------------------------------------------
__global__ __launch_bounds__(256) void k_gat(
    const float* __restrict__ xsrc_s, const int* __restrict__ pfx_s, const int* __restrict__ csr_s,
    const float* __restrict__ Ws_s, const float* __restrict__ bs_s,
    const float* __restrict__ Wd_s, const float* __restrict__ bd_s,
    const float* __restrict__ at_s,
    const float* __restrict__ Wr_s, const float* __restrict__ br_s,
    const float* __restrict__ xsrc_n, const int* __restrict__ pfx_n, const int* __restrict__ csr_n,
    const float* __restrict__ Ws_n, const float* __restrict__ bs_n,
    const float* __restrict__ Wd_n, const float* __restrict__ bd_n,
    const float* __restrict__ at_n,
    const float* __restrict__ Wr_n, const float* __restrict__ br_n,
    const float* __restrict__ x_ag,
    unsigned short* __restrict__ xcat, int n_dst, int gNs)
{
    const bool seen = (int)blockIdx.x < gNs;
    const float* x_src = seen ? xsrc_s : xsrc_n;
    const int*   pfx   = seen ? pfx_s  : pfx_n;
    const int*   csr   = seen ? csr_s  : csr_n;
    const float* Ws    = seen ? Ws_s   : Ws_n;
    const float* bs    = seen ? bs_s   : bs_n;
    const float* Wd    = seen ? Wd_s   : Wd_n;
    const float* bd    = seen ? bd_s   : bd_n;
    const float* at    = seen ? at_s   : at_n;
    const float* Wr    = seen ? Wr_s   : Wr_n;
    const float* br    = seen ? br_s   : br_n;
    const int col = seen ? 0 : 256;
    const int blk = seen ? (int)blockIdx.x : (int)blockIdx.x - gNs;

    const int t = threadIdx.x;
    const int wave = t >> 6, lane = t & 63;
    const int d0 = lane * 4;

    // ---- gather the wave's 4 agent rows: lane L = feat (L&15) of node L>>4
    int gnode = blk * 16 + ((lane >> 4) << 2) + wave;
    int gn = (gnode < n_dst) ? gnode : (n_dst - 1);
    float xag = x_ag[(size_t)gn * 16 + (lane & 15)];

    // ---- prefetch the 4 nodes' edge ranges (overlaps fd/fr pass)
    int e_start[4], e_end[4];
#pragma unroll
    for (int j = 0; j < 4; ++j) {
        int nd = blk * 16 + j * 4 + wave;
        nd = (nd < n_dst) ? nd : (n_dst - 1);
        e_end[j]   = pfx[nd];
        e_start[j] = nd ? pfx[nd - 1] : 0;
    }

    // ---- fd/fr for all 4 nodes in ONE pass over the 32 weight rows (packed)
    f32x2 fd01[4], fd23[4], fr01[4], fr23[4];
    {
        float4 bdv = *(const float4*)&bd[d0];
        float4 brv = *(const float4*)&br[d0];
#pragma unroll
        for (int j = 0; j < 4; ++j) {
            fd01[j] = (f32x2){bdv.x, bdv.y}; fd23[j] = (f32x2){bdv.z, bdv.w};
            fr01[j] = (f32x2){brv.x, brv.y}; fr23[j] = (f32x2){brv.z, brv.w};
        }
#pragma unroll
        for (int k = 0; k < 16; ++k) {
            float4 wd = *(const float4*)&Wd[k * 256 + d0];
            float4 wr = *(const float4*)&Wr[k * 256 + d0];
            f32x2 wd01 = {wd.x, wd.y}, wd23 = {wd.z, wd.w};
            f32x2 wr01 = {wr.x, wr.y}, wr23 = {wr.z, wr.w};
#pragma unroll
            for (int j = 0; j < 4; ++j) {
                f32x2 xk = splat2(rlane(xag, j * 16 + k));
                fd01[j] = pkfma(xk, wd01, fd01[j]);
                fd23[j] = pkfma(xk, wd23, fd23[j]);
                fr01[j] = pkfma(xk, wr01, fr01[j]);
                fr23[j] = pkfma(xk, wr23, fr23[j]);
            }
        }
    }

    // ---- wave-lifetime edge-loop constants (packed pairs)
    f32x2 ws01[8], ws23[8];
#pragma unroll
    for (int k = 0; k < 8; ++k) {
        float4 w = *(const float4*)&Ws[k * 256 + d0];
        ws01[k] = (f32x2){w.x, w.y};
        ws23[k] = (f32x2){w.z, w.w};
    }
    f32x2 bs01, bs23, at01, at23;
    {
        float4 b4 = *(const float4*)&bs[d0];
        float4 a4 = *(const float4*)&at[d0];
        bs01 = (f32x2){b4.x, b4.y}; bs23 = (f32x2){b4.z, b4.w};
        at01 = (f32x2){a4.x, a4.y}; at23 = (f32x2){a4.z, a4.w};
    }

#pragma unroll
    for (int rep = 0; rep < 4; ++rep) {
        const int node = blk * 16 + rep * 4 + wave;
        if (node >= n_dst) continue;

        const int start = e_start[rep];
        const int deg   = e_end[rep] - start;
        const f32x2 fd01r = fd01[rep], fd23r = fd23[rep];

        float l = 0.f;
        f32x2 a01 = {0.f, 0.f}, a23 = {0.f, 0.f};

        if (deg > 0) {
            const int gs = lane >> 3;   // edge slot 0..7 within chunk
            const int w8 = lane & 7;    // word within the 8-float row

            int e0 = (gs < deg) ? gs : deg - 1;
            int i0 = csr[start + e0];
            float r0 = x_src[(size_t)i0 * 8 + w8];        // 8 rows in flight
            int e1 = (8 + gs < deg) ? 8 + gs : deg - 1;
            int i1 = csr[start + e1];

            for (int base = 0; base < deg; base += 8) {
                float r1 = x_src[(size_t)i1 * 8 + w8];
                int e2 = base + 16 + gs; e2 = (e2 < deg) ? e2 : deg - 1;
                int i2 = csr[start + e2];

#pragma unroll
                for (int j = 0; j < 8; ++j) {
                    if (base + j < deg) {      // wave-uniform -> scalar branch
                        f32x2 x0 = splat2(rlane(r0, j * 8 + 0));
                        f32x2 x1 = splat2(rlane(r0, j * 8 + 1));
                        f32x2 x2 = splat2(rlane(r0, j * 8 + 2));
                        f32x2 x3 = splat2(rlane(r0, j * 8 + 3));
                        f32x2 x4 = splat2(rlane(r0, j * 8 + 4));
                        f32x2 x5 = splat2(rlane(r0, j * 8 + 5));
                        f32x2 x6 = splat2(rlane(r0, j * 8 + 6));
                        f32x2 x7 = splat2(rlane(r0, j * 8 + 7));

                        f32x2 fs01 = bs01, fs23 = bs23;
                        fs01 = pkfma(x0, ws01[0], fs01); fs23 = pkfma(x0, ws23[0], fs23);
                        fs01 = pkfma(x1, ws01[1], fs01); fs23 = pkfma(x1, ws23[1], fs23);
                        fs01 = pkfma(x2, ws01[2], fs01); fs23 = pkfma(x2, ws23[2], fs23);
                        fs01 = pkfma(x3, ws01[3], fs01); fs23 = pkfma(x3, ws23[3], fs23);
                        fs01 = pkfma(x4, ws01[4], fs01); fs23 = pkfma(x4, ws23[4], fs23);
                        fs01 = pkfma(x5, ws01[5], fs01); fs23 = pkfma(x5, ws23[5], fs23);
                        fs01 = pkfma(x6, ws01[6], fs01); fs23 = pkfma(x6, ws23[6], fs23);
                        fs01 = pkfma(x7, ws01[7], fs01); fs23 = pkfma(x7, ws23[7], fs23);

                        // leaky relu of (fs+fd): max(v, 0.2v), packed
                        f32x2 t01 = fs01 + fd01r;
                        f32x2 t23 = fs23 + fd23r;
                        t01 = __builtin_elementwise_max(t01, NEG * t01);
                        t23 = __builtin_elementwise_max(t23, NEG * t23);

                        f32x2 scp = t01 * at01;
                        scp = pkfma(t23, at23, scp);
                        float sc = scp.x + scp.y;
                        sc = rowsum16(sc);

                        float p = __expf(sc);   // no max shift: |sc| bounded
                        l += p;
                        f32x2 pp = splat2(p);
                        a01 = pkfma(pp, fs01, a01);
                        a23 = pkfma(pp, fs23, a23);
                    }
                }
                r0 = r1; i1 = i2;
            }
        }

        float inv = (l > 0.f) ? 1.f / l : 0.f;   // zero in-degree -> rst = 0
        ushort4 o;
        o.x = f2bf(fmaxf(fmaf(a01.x, inv, fr01[rep].x), 0.f));
        o.y = f2bf(fmaxf(fmaf(a01.y, inv, fr01[rep].y), 0.f));
        o.z = f2bf(fmaxf(fmaf(a23.x, inv, fr23[rep].x), 0.f));
        o.w = f2bf(fmaxf(fmaf(a23.y, inv, fr23[rep].y), 0.f));
        *(ushort4*)&xcat[(size_t)node * 512 + col + d0] = o;
    }
}

// ---------------------------------------------------------------------------
// out = relu(X[M,512]bf16 @ W[512,256]bf16 + b) via mfma_f32_16x16x32_bf16.
// Block = 4 waves: rows rbase..rbase+15, wave w covers cols 64w..64w+63.
// A/B frags straight from L2 (no LDS). D: col n=lane&15, row m=q*4+reg.
// ---------------------------------------------------------------------------
__global__ __launch_bounds__(256) void k_mlp(
    const unsigned short* __restrict__ X, const unsigned short* __restrict__ Wt,
    const float* __restrict__ b, float* __restrict__ out, int M)
{
    const int t = threadIdx.x;
    const int wave = t >> 6, lane = t & 63;
    const int m16 = lane & 15, q = lane >> 4;
    const int rbase = blockIdx.x * 16;
    const int nbase = wave * 64;

    int rowa = rbase + m16; if (rowa >= M) rowa = M - 1;
    const unsigned short* xp = X + (size_t)rowa * 512 + q * 8;
    const unsigned short* w0 = Wt + (size_t)(nbase + m16) * 512 + q * 8;
    const unsigned short* w1 = w0 + 16 * 512;
    const unsigned short* w2 = w0 + 32 * 512;
    const unsigned short* w3 = w0 + 48 * 512;

    f32x4 ac0 = {0.f, 0.f, 0.f, 0.f}, ac1 = ac0, ac2 = ac0, ac3 = ac0;

#pragma unroll
    for (int k0 = 0; k0 < 512; k0 += 32) {
        bf16x8 a  = *(const bf16x8*)(xp + k0);
        bf16x8 b0 = *(const bf16x8*)(w0 + k0);
        bf16x8 b1 = *(const bf16x8*)(w1 + k0);
        bf16x8 b2 = *(const bf16x8*)(w2 + k0);
        bf16x8 b3 = *(const bf16x8*)(w3 + k0);
        ac0 = __builtin_amdgcn_mfma_f32_16x16x32_bf16(a, b0, ac0, 0, 0, 0);
        ac1 = __builtin_amdgcn_mfma_f32_16x16x32_bf16(a, b1, ac1, 0, 0, 0);
        ac2 = __builtin_amdgcn_mfma_f32_16x16x32_bf16(a, b2, ac2, 0, 0, 0);
        ac3 = __builtin_amdgcn_mfma_f32_16x16x32_bf16(a, b3, ac3, 0, 0, 0);
    }

#define EPI(AC, J) { \
        int coln = nbase + (J) * 16 + m16; \
        float bias = b[coln]; \
        _Pragma("unroll") \
        for (int r = 0; r < 4; ++r) { \
            int orow = rbase + q * 4 + r; \
            if (orow < M) \
                out[(size_t)orow * 256 + coln] = fmaxf(AC[r] + bias, 0.f); \
        } }
    EPI(ac0, 0) EPI(ac1, 1) EPI(ac2, 2) EPI(ac3, 3)
#undef EPI
}

// ---------------------------------------------------------------------------
extern "C" void kernel_launch(void* const* d_in, const int* in_sizes, int n_in,
                              void* d_out, int out_size, void* d_ws, size_t ws_size,
                              hipStream_t stream) {
    const float* x_gt   = (const float*)d_in[0];
    const float* x_ubs  = (const float*)d_in[1];
    const float* x_ag   = (const float*)d_in[2];
    const int* seen_src = (const int*)d_in[3];
    const int* seen_dst = (const int*)d_in[4];
    const int* near_src = (const int*)d_in[5];
    const int* near_dst = (const int*)d_in[6];
    const float* Ws_s = (const float*)d_in[7];  const float* bs_s = (const float*)d_in[8];
    const float* Wd_s = (const float*)d_in[9];  const float* bd_s = (const float*)d_in[10];
    const float* at_s = (const float*)d_in[11];
    const float* Wr_s = (const float*)d_in[12]; const float* br_s = (const float*)d_in[13];
    const float* Ws_n = (const float*)d_in[14]; const float* bs_n = (const float*)d_in[15];
    const float* Wd_n = (const float*)d_in[16]; const float* bd_n = (const float*)d_in[17];
    const float* at_n = (const float*)d_in[18];
    const float* Wr_n = (const float*)d_in[19]; const float* br_n = (const float*)d_in[20];
    const float* W_a  = (const float*)d_in[21]; const float* b_a  = (const float*)d_in[22];

    const int n_ag = in_sizes[2] / 16;
    const int E_s  = in_sizes[3];
    const int E_n  = in_sizes[5];

    char* ws = (char*)d_ws;
    int* cur_s = (int*)ws;              ws += (size_t)n_ag * 4;
    int* cur_n = (int*)ws;              ws += (size_t)n_ag * 4;
    int* csr_s = (int*)ws;              ws += (size_t)E_s * 4;
    int* csr_n = (int*)ws;              ws += (size_t)E_n * 4;
    unsigned short* xcat = (unsigned short*)ws;  ws += (size_t)n_ag * 512 * 2;
    unsigned short* Wt   = (unsigned short*)ws;  // [256][512] bf16

    hipMemsetAsync(cur_s, 0, (size_t)n_ag * 8, stream);  // cur_s, cur_n contiguous

    int gE = (E_s + E_n + 255) / 256;
    k_hist_wt<<<gE, 256, 0, stream>>>(seen_dst, E_s, near_dst, E_n, cur_s, cur_n, W_a, Wt);
    k_scan2<<<2, 1024, 0, stream>>>(cur_s, n_ag, cur_n, n_ag);
    k_scatter<<<gE, 256, 0, stream>>>(seen_src, seen_dst, E_s, near_src, near_dst, E_n,
                                      cur_s, cur_n, csr_s, csr_n);

    int gN = (n_ag + 15) / 16;   // 16 nodes per block (4 waves x 4 nodes)
    k_gat<<<2 * gN, 256, 0, stream>>>(
        x_gt,  cur_s, csr_s, Ws_s, bs_s, Wd_s, bd_s, at_s, Wr_s, br_s,
        x_ubs, cur_n, csr_n, Ws_n, bs_n, Wd_n, bd_n, at_n, Wr_n, br_n,
        x_ag, xcat, n_ag, gN);

    k_mlp<<<(n_ag + 15) / 16, 256, 0, stream>>>(xcat, Wt, b_a, (float*)d_out, n_ag);
}